// Round 11
// baseline (771.081 us; speedup 1.0000x reference)
//
#include <hip/hip_runtime.h>
#include <hip/hip_cooperative_groups.h>

namespace cg = cooperative_groups;

#define B_N 256
#define IC_N 1152
#define J_N 10
#define D_N 16

typedef __attribute__((ext_vector_type(8))) short short8;
typedef __attribute__((ext_vector_type(4))) float floatx4;

union u4s8 { uint4 u; short8 s; };

__device__ __forceinline__ float bf_lo(unsigned int u){
  union { unsigned int i; float f; } c; c.i = u << 16; return c.f;
}
__device__ __forceinline__ float bf_hi(unsigned int u){
  union { unsigned int i; float f; } c; c.i = u & 0xffff0000u; return c.f;
}
__device__ __forceinline__ unsigned int rne16(float f){
  union { float ff; unsigned int i; } c; c.ff = f;
  return (c.i + 0x7FFFu + ((c.i >> 16) & 1u)) >> 16;
}
__device__ __forceinline__ unsigned int pack_rne(float lo, float hi){
  return rne16(lo) | (rne16(hi) << 16);
}
__device__ __forceinline__ unsigned int pack_trunc(float lo, float hi){
  union { float f; unsigned int u; } a, b; a.f = lo; b.f = hi;
  return __builtin_amdgcn_perm(b.u, a.u, 0x07060302u);
}

// ================= fused cooperative kernel (grid 256 x 640) ================
// btile = bid&15 (16 b); ch = bid>>4 owns 16-i tiles [(9ch+1)/2,(9ch+10)/2)
// (alternating 4/5 tiles = 64/80 i). Fragment layouts = R6/R8/R9 verified.
__global__ __launch_bounds__(640, 5) void caps_fused(
    const float* __restrict__ W, const float* __restrict__ x,
    uint4* __restrict__ wsf, uint4* __restrict__ wcc2,
    uint4* __restrict__ xbf_ib, uint4* __restrict__ xbf_bi,
    float* __restrict__ s_part,          // [ch 16][b 256][j 10][d 16]
    unsigned int* __restrict__ vsbf_u,   // accumulated v-sum, bf16 frag layout
    float* __restrict__ out)
{
  __shared__ float smem[10 * 80 * 17];   // 54.4 KB (ccl / prep scratch)
  cg::grid_group grid = cg::this_grid();

  const int bid = blockIdx.x;
  const int tid = threadIdx.x;
  const int wave = tid >> 6;             // = j
  const int lane = tid & 63;
  const int quad = lane >> 4;
  const int col  = lane & 15;

  // ---------------- prep (virtual blocks 0..1007, step 256) ----------------
  unsigned int* lw = (unsigned int*)smem;
  unsigned int* tx = (unsigned int*)smem;
  for (int vb = bid; vb < 1008; vb += 256) {
    if (tid < 256) {
      if (vb < 720) {                    // W tile (j, itile16) staged to LDS
        const int j = vb / 72, itile = vb % 72;
        const float4* Wt = (const float4*)(W + ((size_t)(j * IC_N + itile * 16) << 7));
        #pragma unroll
        for (int h = 0; h < 2; ++h) {
          const float4 f = Wt[h * 256 + tid];
          lw[(h * 256 + tid) * 2]     = pack_rne(f.x, f.y);
          lw[(h * 256 + tid) * 2 + 1] = pack_rne(f.z, f.w);
        }
      } else {                           // x: direct xbf_bi + LDS transpose
        const int vb2 = vb - 720;
        const int b0p = (vb2 / 18) * 16;
        const int i0p = (vb2 % 18) * 64;
        #pragma unroll
        for (int r = 0; r < 4; ++r) {
          const int bl = r * 4 + (tid >> 6);
          const int il = tid & 63;
          const float4* sp = (const float4*)(x + ((size_t)((b0p + bl) * IC_N + i0p + il) << 3));
          const float4 a = sp[0], c = sp[1];
          uint4 q;
          q.x = pack_rne(a.x, a.y); q.y = pack_rne(a.z, a.w);
          q.z = pack_rne(c.x, c.y); q.w = pack_rne(c.z, c.w);
          xbf_bi[(size_t)(b0p + bl) * IC_N + i0p + il] = q;
          tx[0 * 1088 + il * 17 + bl] = q.x; tx[1 * 1088 + il * 17 + bl] = q.y;
          tx[2 * 1088 + il * 17 + bl] = q.z; tx[3 * 1088 + il * 17 + bl] = q.w;
        }
      }
    }
    __syncthreads();
    if (tid < 256) {
      if (vb < 720) {
        const int j = vb / 72, itile = vb % 72;
        {  // wsf emit
          const int ktl = tid >> 6, ln = tid & 63;
          const int base = (ktl * 4 + (ln >> 4)) * 64 + (ln & 15) * 4;
          uint4 q;
          q.x = lw[base]; q.y = lw[base + 1]; q.z = lw[base + 2]; q.w = lw[base + 3];
          wsf[((size_t)j * 288 + itile * 4 + ktl) * 64 + ln] = q;
        }
        {  // wcc2 emit
          const int e = tid >> 5, lane2 = tid & 31;
          const int il = lane2 & 15, dbase = (lane2 >> 4) * 8;
          unsigned short h[8];
          #pragma unroll
          for (int k = 0; k < 8; ++k) {
            const unsigned int u = lw[il * 64 + (dbase + k) * 4 + (e >> 1)];
            h[k] = (e & 1) ? (unsigned short)(u >> 16) : (unsigned short)(u & 0xffffu);
          }
          uint4 q;
          q.x = h[0] | ((unsigned int)h[1] << 16);
          q.y = h[2] | ((unsigned int)h[3] << 16);
          q.z = h[4] | ((unsigned int)h[5] << 16);
          q.w = h[6] | ((unsigned int)h[7] << 16);
          wcc2[(((size_t)j * 8 + e) * 72 + itile) * 32 + lane2] = q;
        }
      } else {
        const int vb2 = vb - 720;
        const int b0p = (vb2 / 18) * 16;
        const int i0p = (vb2 % 18) * 64;
        #pragma unroll
        for (int it = 0; it < 4; ++it) {
          const int p  = it * 256 + tid;
          const int il = p >> 4, bl = p & 15;
          uint4 q;
          q.x = tx[0 * 1088 + il * 17 + bl]; q.y = tx[1 * 1088 + il * 17 + bl];
          q.z = tx[2 * 1088 + il * 17 + bl]; q.w = tx[3 * 1088 + il * 17 + bl];
          xbf_ib[(size_t)(i0p + il) * 256 + b0p + bl] = q;
        }
      }
    }
    __syncthreads();
  }
  __threadfence();
  grid.sync();

  // ---------------- 3 routing rounds ----------------
  const int btile = bid & 15, ch = bid >> 4;
  const int b0 = btile << 4;
  const int t0 = (9 * ch + 1) >> 1;      // first 16-i tile
  const int t1 = (9 * ch + 10) >> 1;     // one past last (4 or 5 tiles)
  float* ccl = smem;                     // [j][i_local <=80][b pad17]
  float vacc = 0.f;

  for (int r = 0; r < 3; ++r) {
    if (r > 0) {
      // ---- phase A: cc via per-e MFMAs, epilogue in C-layout regs ----
      short8 av = {0,0,0,0,0,0,0,0};
      if (quad < 2)
        av = *(const short8*)&(((const uint4*)vsbf_u)[((size_t)(b0 + col) * J_N + wave) * 2 + quad]);
      for (int tl = t0; tl < t1; ++tl) {
        uint4 bvq[8];
        #pragma unroll
        for (int e = 0; e < 8; ++e) {
          uint4 q = {0u, 0u, 0u, 0u};
          if (lane < 32)
            q = wcc2[(((size_t)wave * 8 + e) * 72 + tl) * 32 + lane];
          bvq[e] = q;
        }
        uint4 xr[4];
        #pragma unroll
        for (int rr = 0; rr < 4; ++rr)
          xr[rr] = xbf_bi[(size_t)(b0 + quad * 4 + rr) * IC_N + tl * 16 + col];
        floatx4 cc4 = {0.f, 0.f, 0.f, 0.f};
        #pragma unroll
        for (int e = 0; e < 8; ++e) {
          u4s8 bv; bv.u = bvq[e];
          floatx4 tf = {0.f, 0.f, 0.f, 0.f};
          tf = __builtin_amdgcn_mfma_f32_16x16x32_bf16(av, bv.s, tf, 0, 0, 0);
          #pragma unroll
          for (int rr = 0; rr < 4; ++rr) {
            const unsigned int u = ((const unsigned int*)&xr[rr])[e >> 1];
            const float xe = (e & 1) ? bf_hi(u) : bf_lo(u);
            cc4[rr] += tf[rr] * xe;
          }
        }
        #pragma unroll
        for (int rr = 0; rr < 4; ++rr)
          ccl[(wave * 80 + (tl - t0) * 16 + col) * 17 + quad * 4 + rr] = cc4[rr];
      }
      __syncthreads();
      const int ni16 = (t1 - t0) * 256;          // (i_local, b) pairs
      for (int p = tid; p < ni16; p += 640) {    // softmax over j, in place
        const int i = p >> 4, b = p & 15;
        float cc[10];
        #pragma unroll
        for (int j = 0; j < 10; ++j) cc[j] = ccl[(j * 80 + i) * 17 + b];
        float m = cc[0];
        #pragma unroll
        for (int j = 1; j < 10; ++j) m = fmaxf(m, cc[j]);
        float den = 0.f;
        #pragma unroll
        for (int j = 0; j < 10; ++j) { cc[j] = __expf(cc[j] - m); den += cc[j]; }
        const float rd = __builtin_amdgcn_rcpf(den);
        #pragma unroll
        for (int j = 0; j < 10; ++j) ccl[(j * 80 + i) * 17 + b] = cc[j] * rd;
      }
      __syncthreads();
    }

    // ---- phase B: s[b,d] += (c*x) @ Ws over this chunk's tiles ----
    floatx4 acc = {0.f, 0.f, 0.f, 0.f};
    for (int tl = t0; tl < t1; ++tl) {
      uint4 xq[4], wf[4];
      float cv[4];
      #pragma unroll
      for (int k = 0; k < 4; ++k) {
        const int ig = tl * 16 + k * 4 + quad;
        xq[k] = xbf_ib[(size_t)ig * 256 + b0 + col];
        wf[k] = wsf[((size_t)wave * 288 + tl * 4 + k) * 64 + lane];
        cv[k] = (r > 0) ? ccl[(wave * 80 + (tl - t0) * 16 + k * 4 + quad) * 17 + col]
                        : 0.1f;
      }
      #pragma unroll
      for (int k = 0; k < 4; ++k) {
        short8 af;
        unsigned int* aq = (unsigned int*)&af;
        aq[0] = pack_trunc(bf_lo(xq[k].x) * cv[k], bf_hi(xq[k].x) * cv[k]);
        aq[1] = pack_trunc(bf_lo(xq[k].y) * cv[k], bf_hi(xq[k].y) * cv[k]);
        aq[2] = pack_trunc(bf_lo(xq[k].z) * cv[k], bf_hi(xq[k].z) * cv[k]);
        aq[3] = pack_trunc(bf_lo(xq[k].w) * cv[k], bf_hi(xq[k].w) * cv[k]);
        u4s8 bw; bw.u = wf[k];
        acc = __builtin_amdgcn_mfma_f32_16x16x32_bf16(af, bw.s, acc, 0, 0, 0);
      }
    }
    {  // s_part[ch][b0+quad*4+rr][j][d=col]
      float* sp = s_part + (((size_t)ch * 256 + b0 + quad * 4) * 10 + wave) * 16 + col;
      #pragma unroll
      for (int rr = 0; rr < 4; ++rr) sp[rr * 160] = acc[rr];
    }
    __threadfence();
    grid.sync();

    // ---- reduce over 16 chunks + squash (threads t < 40960) ----
    const int t = bid * 640 + tid;
    if (t < 40960) {
      float s = 0.f;
      #pragma unroll
      for (int c2 = 0; c2 < 16; ++c2) s += s_part[(size_t)c2 * 40960 + t];
      float sq = s * s;
      sq += __shfl_xor(sq, 1, 16);
      sq += __shfl_xor(sq, 2, 16);
      sq += __shfl_xor(sq, 4, 16);
      sq += __shfl_xor(sq, 8, 16);
      const float coef = (sq / (1.f + sq)) * rsqrtf(sq + 1e-7f);
      const float v = coef * s;
      if (r < 2) {
        vacc += v;                       // accumulated v-sum (R7 lesson)
        const float vp = __shfl_down(vacc, 1, 64);
        if (!(t & 1)) vsbf_u[t >> 1] = pack_rne(vacc, vp);
      } else {
        out[t] = v;
      }
    }
    __threadfence();
    grid.sync();
  }
}

// ================= fallback: proven R9 3-kernel pipeline ====================
__global__ __launch_bounds__(256) void caps_prep_fb(
    const float* __restrict__ W, const float* __restrict__ x,
    uint4* __restrict__ wsf, uint4* __restrict__ wcc2,
    uint4* __restrict__ xbf_ib, uint4* __restrict__ xbf_bi,
    float* __restrict__ vsum)
{
  const int tid = threadIdx.x;
  if (blockIdx.x < 720) {
    __shared__ unsigned int lw[1024];
    const int j = blockIdx.x / 72, itile = blockIdx.x % 72;
    const float4* Wt = (const float4*)(W + ((size_t)(j * IC_N + itile * 16) << 7));
    #pragma unroll
    for (int h = 0; h < 2; ++h) {
      const float4 f = Wt[h * 256 + tid];
      lw[(h * 256 + tid) * 2]     = pack_rne(f.x, f.y);
      lw[(h * 256 + tid) * 2 + 1] = pack_rne(f.z, f.w);
    }
    __syncthreads();
    {
      const int ktl = tid >> 6, ln = tid & 63;
      const int base = (ktl * 4 + (ln >> 4)) * 64 + (ln & 15) * 4;
      uint4 q;
      q.x = lw[base]; q.y = lw[base + 1]; q.z = lw[base + 2]; q.w = lw[base + 3];
      wsf[((size_t)j * 288 + itile * 4 + ktl) * 64 + ln] = q;
    }
    {
      const int e = tid >> 5, lane2 = tid & 31;
      const int il = lane2 & 15, dbase = (lane2 >> 4) * 8;
      unsigned short h[8];
      #pragma unroll
      for (int k = 0; k < 8; ++k) {
        const unsigned int u = lw[il * 64 + (dbase + k) * 4 + (e >> 1)];
        h[k] = (e & 1) ? (unsigned short)(u >> 16) : (unsigned short)(u & 0xffffu);
      }
      uint4 q;
      q.x = h[0] | ((unsigned int)h[1] << 16);
      q.y = h[2] | ((unsigned int)h[3] << 16);
      q.z = h[4] | ((unsigned int)h[5] << 16);
      q.w = h[6] | ((unsigned int)h[7] << 16);
      wcc2[(((size_t)j * 8 + e) * 72 + itile) * 32 + lane2] = q;
    }
  } else {
    __shared__ unsigned int tx[4][64 * 17];
    const int xb = blockIdx.x - 720;
    const int t0 = xb * 256 + tid;
    if (t0 < B_N * J_N * D_N) vsum[t0] = 0.f;
    const int b0 = (xb / 18) * 16;
    const int i0 = (xb % 18) * 64;
    #pragma unroll
    for (int r = 0; r < 4; ++r) {
      const int bl = r * 4 + (tid >> 6);
      const int il = tid & 63;
      const float4* sp = (const float4*)(x + ((size_t)((b0 + bl) * IC_N + i0 + il) << 3));
      const float4 a = sp[0], c = sp[1];
      uint4 q;
      q.x = pack_rne(a.x, a.y); q.y = pack_rne(a.z, a.w);
      q.z = pack_rne(c.x, c.y); q.w = pack_rne(c.z, c.w);
      xbf_bi[(size_t)(b0 + bl) * IC_N + i0 + il] = q;
      tx[0][il * 17 + bl] = q.x; tx[1][il * 17 + bl] = q.y;
      tx[2][il * 17 + bl] = q.z; tx[3][il * 17 + bl] = q.w;
    }
    __syncthreads();
    #pragma unroll
    for (int it = 0; it < 4; ++it) {
      const int p  = it * 256 + tid;
      const int il = p >> 4, bl = p & 15;
      uint4 q;
      q.x = tx[0][il * 17 + bl]; q.y = tx[1][il * 17 + bl];
      q.z = tx[2][il * 17 + bl]; q.w = tx[3][il * 17 + bl];
      xbf_ib[(size_t)(i0 + il) * 256 + b0 + bl] = q;
    }
  }
}

__global__ __launch_bounds__(640, 5) void caps_pass_fb(
    const uint4* __restrict__ xbf_ib, const uint4* __restrict__ xbf_bi,
    const uint4* __restrict__ wsf, const uint4* __restrict__ wcc2,
    const uint4* __restrict__ vsbf, float* __restrict__ s_part, const int round)
{
  __shared__ float ccl[10 * 16 * 17];
  const int tid  = threadIdx.x;
  const int wave = tid >> 6;
  const int lane = tid & 63;
  const int quad = lane >> 4;
  const int col  = lane & 15;
  const int b0   = blockIdx.x << 4;
  const int i0   = blockIdx.y << 4;

  if (round > 0) {
    short8 av = {0,0,0,0,0,0,0,0};
    if (quad < 2)
      av = *(const short8*)&vsbf[((size_t)(b0 + col) * J_N + wave) * 2 + quad];
    uint4 bvq[8];
    #pragma unroll
    for (int e = 0; e < 8; ++e) {
      uint4 q = {0u, 0u, 0u, 0u};
      if (lane < 32)
        q = wcc2[(((size_t)wave * 8 + e) * 72 + blockIdx.y) * 32 + lane];
      bvq[e] = q;
    }
    uint4 xr[4];
    #pragma unroll
    for (int r = 0; r < 4; ++r)
      xr[r] = xbf_bi[(size_t)(b0 + quad * 4 + r) * IC_N + i0 + col];
    floatx4 cc4 = {0.f, 0.f, 0.f, 0.f};
    #pragma unroll
    for (int e = 0; e < 8; ++e) {
      u4s8 bv; bv.u = bvq[e];
      floatx4 tf = {0.f, 0.f, 0.f, 0.f};
      tf = __builtin_amdgcn_mfma_f32_16x16x32_bf16(av, bv.s, tf, 0, 0, 0);
      #pragma unroll
      for (int r = 0; r < 4; ++r) {
        const unsigned int u = ((const unsigned int*)&xr[r])[e >> 1];
        const float xe = (e & 1) ? bf_hi(u) : bf_lo(u);
        cc4[r] += tf[r] * xe;
      }
    }
    #pragma unroll
    for (int r = 0; r < 4; ++r)
      ccl[(wave * 16 + col) * 17 + quad * 4 + r] = cc4[r];
    __syncthreads();
    if (tid < 256) {
      const int i = tid >> 4, b = tid & 15;
      float cc[10];
      #pragma unroll
      for (int j = 0; j < 10; ++j) cc[j] = ccl[(j * 16 + i) * 17 + b];
      float m = cc[0];
      #pragma unroll
      for (int j = 1; j < 10; ++j) m = fmaxf(m, cc[j]);
      float den = 0.f;
      #pragma unroll
      for (int j = 0; j < 10; ++j) { cc[j] = __expf(cc[j] - m); den += cc[j]; }
      const float rd = __builtin_amdgcn_rcpf(den);
      #pragma unroll
      for (int j = 0; j < 10; ++j) ccl[(j * 16 + i) * 17 + b] = cc[j] * rd;
    }
    __syncthreads();
  }

  floatx4 acc = {0.f, 0.f, 0.f, 0.f};
  uint4 xq[4], wf[4];
  float cv[4];
  #pragma unroll
  for (int kt = 0; kt < 4; ++kt) {
    const int il = kt * 4 + quad;
    xq[kt] = xbf_ib[(size_t)(i0 + il) * 256 + b0 + col];
    wf[kt] = wsf[((size_t)wave * 288 + (blockIdx.y << 2) + kt) * 64 + lane];
    cv[kt] = (round > 0) ? ccl[(wave * 16 + il) * 17 + col] : 0.1f;
  }
  #pragma unroll
  for (int kt = 0; kt < 4; ++kt) {
    short8 af;
    unsigned int* aq = (unsigned int*)&af;
    aq[0] = pack_trunc(bf_lo(xq[kt].x) * cv[kt], bf_hi(xq[kt].x) * cv[kt]);
    aq[1] = pack_trunc(bf_lo(xq[kt].y) * cv[kt], bf_hi(xq[kt].y) * cv[kt]);
    aq[2] = pack_trunc(bf_lo(xq[kt].z) * cv[kt], bf_hi(xq[kt].z) * cv[kt]);
    aq[3] = pack_trunc(bf_lo(xq[kt].w) * cv[kt], bf_hi(xq[kt].w) * cv[kt]);
    u4s8 bw; bw.u = wf[kt];
    acc = __builtin_amdgcn_mfma_f32_16x16x32_bf16(af, bw.s, acc, 0, 0, 0);
  }
  float* sp = s_part + ((((size_t)blockIdx.x * 10 + wave) * 16 + quad * 4) * 72
                        + blockIdx.y) * 16 + col;
  #pragma unroll
  for (int r = 0; r < 4; ++r) sp[(size_t)r * 72 * 16] = acc[r];
}

__global__ __launch_bounds__(256) void caps_squash_fb(
    const float* __restrict__ s_part, float* __restrict__ vsum,
    unsigned int* __restrict__ vsbf_u, float* __restrict__ out, const int round)
{
  const int tid  = threadIdx.x;
  const int w    = tid >> 6;
  const int lane = tid & 63;
  const int bj   = blockIdx.x * 4 + w;
  const int b    = bj / 10, j = bj - b * 10;
  const int btile = b >> 4, brem = b & 15;
  const float* base = s_part + (((size_t)btile * 10 + j) * 16 + brem) * 1152;
  float acc = 0.f;
  #pragma unroll
  for (int q = 0; q < 18; ++q) acc += base[q * 64 + lane];
  acc += __shfl_xor(acc, 16, 64);
  acc += __shfl_xor(acc, 32, 64);
  const float s = acc;
  float sq = s * s;
  sq += __shfl_xor(sq, 1, 16);
  sq += __shfl_xor(sq, 2, 16);
  sq += __shfl_xor(sq, 4, 16);
  sq += __shfl_xor(sq, 8, 16);
  const float coef = (sq / (1.f + sq)) * rsqrtf(sq + 1e-7f);
  const float v = coef * s;
  if (round < 2) {
    const float vprev = (lane < 16) ? vsum[bj * 16 + lane] : 0.f;
    const float vt = vprev + v;
    const float vtn = __shfl_down(vt, 1, 64);
    if (lane < 16) {
      vsum[bj * 16 + lane] = vt;
      if (!(lane & 1))
        vsbf_u[bj * 8 + (lane >> 1)] = pack_rne(vt, vtn);
    }
  } else if (lane < 16) {
    out[bj * 16 + lane] = v;
  }
}

extern "C" void kernel_launch(void* const* d_in, const int* in_sizes, int n_in,
                              void* d_out, int out_size, void* d_ws, size_t ws_size,
                              hipStream_t stream)
{
  const float* x_p = (const float*)d_in[0];   // [256][1152][8] fp32
  const float* W_p = (const float*)d_in[1];   // [10][1152][16][8] fp32

  // ws: wsf 2.95M | wcc2 2.95M | xbf_ib 4.72M | xbf_bi 4.72M
  //     | s_part 11.8M (fallback size; fused uses first 2.62M) | vsum | vsbf
  uint4* wsf    = (uint4*)d_ws;
  uint4* wcc2   = wsf + 184320;
  uint4* xbf_ib = wcc2 + 184320;
  uint4* xbf_bi = xbf_ib + 294912;
  float* s_prt  = (float*)(xbf_bi + 294912);          // 2949120 f
  float* vsum   = s_prt + 2949120;                    // 40960 f
  unsigned int* vsbf_u = (unsigned int*)(vsum + 40960);
  float* out_p  = (float*)d_out;

  void* args[] = { (void*)&W_p, (void*)&x_p, (void*)&wsf, (void*)&wcc2,
                   (void*)&xbf_ib, (void*)&xbf_bi, (void*)&s_prt,
                   (void*)&vsbf_u, (void*)&out_p };
  hipError_t err = hipLaunchCooperativeKernel((const void*)caps_fused,
                                              dim3(256), dim3(640),
                                              args, 0, stream);
  if (err != hipSuccess) {
    (void)hipGetLastError();            // clear sticky error, take proven path
    caps_prep_fb<<<dim3(1008), dim3(256), 0, stream>>>(W_p, x_p, wsf, wcc2,
                                                       xbf_ib, xbf_bi, vsum);
    for (int r = 0; r < 3; ++r) {
      caps_pass_fb<<<dim3(16, 72), dim3(640), 0, stream>>>(
          xbf_ib, xbf_bi, wsf, wcc2, (const uint4*)vsbf_u, s_prt, r);
      caps_squash_fb<<<dim3(640), dim3(256), 0, stream>>>(
          s_prt, vsum, vsbf_u, out_p, r);
    }
  }
}

// Round 12
// 167.408 us; speedup vs baseline: 4.6060x; 4.6060x over previous
//
#include <hip/hip_runtime.h>

#define B_N 256
#define IC_N 1152
#define J_N 10
#define D_N 16
#define NBLK 576            // 16 btiles x 36 chunks
#define NWORK 64            // last-arriving blocks that run the fused squash

typedef __attribute__((ext_vector_type(8))) short short8;
typedef __attribute__((ext_vector_type(4))) float floatx4;

union u4s8 { uint4 u; short8 s; };

__device__ __forceinline__ float bf_lo(unsigned int u){
  union { unsigned int i; float f; } c; c.i = u << 16; return c.f;
}
__device__ __forceinline__ float bf_hi(unsigned int u){
  union { unsigned int i; float f; } c; c.i = u & 0xffff0000u; return c.f;
}
__device__ __forceinline__ unsigned int rne16(float f){
  union { float ff; unsigned int i; } c; c.ff = f;
  return (c.i + 0x7FFFu + ((c.i >> 16) & 1u)) >> 16;
}
__device__ __forceinline__ unsigned int pack_rne(float lo, float hi){
  return rne16(lo) | (rne16(hi) << 16);
}
__device__ __forceinline__ unsigned int pack_trunc(float lo, float hi){
  union { float f; unsigned int u; } a, b; a.f = lo; b.f = hi;
  return __builtin_amdgcn_perm(b.u, a.u, 0x07060302u);
}

// prep (R9-proven): W read once -> wsf/wcc2 frags; x -> xbf_ib + xbf_bi;
// zero vsum + the 3 round-tickets.
__global__ __launch_bounds__(256) void caps_prep(
    const float* __restrict__ W, const float* __restrict__ x,
    uint4* __restrict__ wsf, uint4* __restrict__ wcc2,
    uint4* __restrict__ xbf_ib, uint4* __restrict__ xbf_bi,
    float* __restrict__ vsum, unsigned int* __restrict__ cnt)
{
  const int tid = threadIdx.x;
  if (blockIdx.x == 1007 && tid < 4) cnt[tid] = 0u;
  if (blockIdx.x < 720) {
    __shared__ unsigned int lw[1024];
    const int j = blockIdx.x / 72, itile = blockIdx.x % 72;
    const float4* Wt = (const float4*)(W + ((size_t)(j * IC_N + itile * 16) << 7));
    #pragma unroll
    for (int h = 0; h < 2; ++h) {
      const float4 f = Wt[h * 256 + tid];
      lw[(h * 256 + tid) * 2]     = pack_rne(f.x, f.y);
      lw[(h * 256 + tid) * 2 + 1] = pack_rne(f.z, f.w);
    }
    __syncthreads();
    {  // wsf emit (layout verified R5..R9)
      const int ktl = tid >> 6, ln = tid & 63;
      const int base = (ktl * 4 + (ln >> 4)) * 64 + (ln & 15) * 4;
      uint4 q;
      q.x = lw[base]; q.y = lw[base + 1]; q.z = lw[base + 2]; q.w = lw[base + 3];
      wsf[((size_t)j * 288 + itile * 4 + ktl) * 64 + ln] = q;
    }
    {  // wcc2 emit (layout verified R6..R9)
      const int e = tid >> 5, lane2 = tid & 31;
      const int il = lane2 & 15, dbase = (lane2 >> 4) * 8;
      unsigned short h[8];
      #pragma unroll
      for (int k = 0; k < 8; ++k) {
        const unsigned int u = lw[il * 64 + (dbase + k) * 4 + (e >> 1)];
        h[k] = (e & 1) ? (unsigned short)(u >> 16) : (unsigned short)(u & 0xffffu);
      }
      uint4 q;
      q.x = h[0] | ((unsigned int)h[1] << 16);
      q.y = h[2] | ((unsigned int)h[3] << 16);
      q.z = h[4] | ((unsigned int)h[5] << 16);
      q.w = h[6] | ((unsigned int)h[7] << 16);
      wcc2[(((size_t)j * 8 + e) * 72 + itile) * 32 + lane2] = q;
    }
  } else {
    __shared__ unsigned int tx[4][64 * 17];
    const int xb = blockIdx.x - 720;
    const int t0 = xb * 256 + tid;
    if (t0 < B_N * J_N * D_N) vsum[t0] = 0.f;
    const int b0 = (xb / 18) * 16;
    const int i0 = (xb % 18) * 64;
    #pragma unroll
    for (int r = 0; r < 4; ++r) {
      const int bl = r * 4 + (tid >> 6);
      const int il = tid & 63;
      const float4* sp = (const float4*)(x + ((size_t)((b0 + bl) * IC_N + i0 + il) << 3));
      const float4 a = sp[0], c = sp[1];
      uint4 q;
      q.x = pack_rne(a.x, a.y); q.y = pack_rne(a.z, a.w);
      q.z = pack_rne(c.x, c.y); q.w = pack_rne(c.z, c.w);
      xbf_bi[(size_t)(b0 + bl) * IC_N + i0 + il] = q;
      tx[0][il * 17 + bl] = q.x; tx[1][il * 17 + bl] = q.y;
      tx[2][il * 17 + bl] = q.z; tx[3][il * 17 + bl] = q.w;
    }
    __syncthreads();
    #pragma unroll
    for (int it = 0; it < 4; ++it) {
      const int p  = it * 256 + tid;
      const int il = p >> 4, bl = p & 15;
      uint4 q;
      q.x = tx[0][il * 17 + bl]; q.y = tx[1][il * 17 + bl];
      q.z = tx[2][il * 17 + bl]; q.w = tx[3][il * 17 + bl];
      xbf_ib[(size_t)(i0 + il) * 256 + b0 + bl] = q;
    }
  }
}

// One fused round: R8-proven pass (32-i chunks, hoisted loads) + last-64-
// blocks squash tail. Bounded spin: workers already finished their own work;
// no block's completion depends on another's scheduling (no deadlock).
__global__ __launch_bounds__(640, 6) void caps_round(
    const uint4* __restrict__ xbf_ib, const uint4* __restrict__ xbf_bi,
    const uint4* __restrict__ wsf, const uint4* __restrict__ wcc2,
    const uint4* __restrict__ vsbf, float* __restrict__ s_part,
    float* __restrict__ vsum, unsigned int* __restrict__ vsbf_u,
    float* __restrict__ out, unsigned int* __restrict__ cnt, const int round)
{
  __shared__ float ccl[10 * 32 * 17];   // 21.8 KB
  __shared__ int tick_s;

  const int tid  = threadIdx.x;
  const int wave = tid >> 6;            // = j
  const int lane = tid & 63;
  const int quad = lane >> 4;
  const int col  = lane & 15;
  const int b0   = blockIdx.x << 4;
  const int i0   = blockIdx.y << 5;     // 32 i per chunk

  if (round > 0) {
    short8 av = {0,0,0,0,0,0,0,0};      // vsum[b=col][d=quad*8+..]; q2,3 K-pad
    if (quad < 2)
      av = *(const short8*)&vsbf[((size_t)(b0 + col) * J_N + wave) * 2 + quad];

    #pragma unroll
    for (int t2 = 0; t2 < 2; ++t2) {
      uint4 bvq[8];
      #pragma unroll
      for (int e = 0; e < 8; ++e) {
        uint4 q = {0u, 0u, 0u, 0u};
        if (lane < 32)
          q = wcc2[(((size_t)wave * 8 + e) * 72 + (blockIdx.y << 1) + t2) * 32 + lane];
        bvq[e] = q;
      }
      uint4 xr[4];
      #pragma unroll
      for (int r = 0; r < 4; ++r)
        xr[r] = xbf_bi[(size_t)(b0 + quad * 4 + r) * IC_N + i0 + t2 * 16 + col];

      floatx4 cc4 = {0.f, 0.f, 0.f, 0.f};
      #pragma unroll
      for (int e = 0; e < 8; ++e) {
        u4s8 bv; bv.u = bvq[e];
        floatx4 tf = {0.f, 0.f, 0.f, 0.f};
        tf = __builtin_amdgcn_mfma_f32_16x16x32_bf16(av, bv.s, tf, 0, 0, 0);
        #pragma unroll
        for (int r = 0; r < 4; ++r) {
          const unsigned int u = ((const unsigned int*)&xr[r])[e >> 1];
          const float xe = (e & 1) ? bf_hi(u) : bf_lo(u);
          cc4[r] += tf[r] * xe;
        }
      }
      #pragma unroll
      for (int r = 0; r < 4; ++r)
        ccl[(wave * 32 + t2 * 16 + col) * 17 + quad * 4 + r] = cc4[r];
    }
    __syncthreads();
    if (tid < 512) {                    // softmax over j per (i,b), in place
      const int i = tid >> 4, b = tid & 15;
      float cc[10];
      #pragma unroll
      for (int j = 0; j < 10; ++j) cc[j] = ccl[(j * 32 + i) * 17 + b];
      float m = cc[0];
      #pragma unroll
      for (int j = 1; j < 10; ++j) m = fmaxf(m, cc[j]);
      float den = 0.f;
      #pragma unroll
      for (int j = 0; j < 10; ++j) { cc[j] = __expf(cc[j] - m); den += cc[j]; }
      const float rd = __builtin_amdgcn_rcpf(den);
      #pragma unroll
      for (int j = 0; j < 10; ++j) ccl[(j * 32 + i) * 17 + b] = cc[j] * rd;
    }
    __syncthreads();
  }

  // Phase B: s[b,d] += (c*x) @ Ws, K=256; 2 hoisted groups of 4
  floatx4 acc = {0.f, 0.f, 0.f, 0.f};
  #pragma unroll
  for (int g = 0; g < 2; ++g) {
    uint4 xq[4], wf[4];
    float cv[4];
    #pragma unroll
    for (int k = 0; k < 4; ++k) {
      const int kt = g * 4 + k;
      const int il = kt * 4 + quad;
      xq[k] = xbf_ib[(size_t)(i0 + il) * 256 + b0 + col];
      wf[k] = wsf[((size_t)wave * 288 + (blockIdx.y << 3) + kt) * 64 + lane];
      cv[k] = (round > 0) ? ccl[(wave * 32 + il) * 17 + col] : 0.1f;
    }
    #pragma unroll
    for (int k = 0; k < 4; ++k) {
      short8 af;
      unsigned int* aq = (unsigned int*)&af;
      aq[0] = pack_trunc(bf_lo(xq[k].x) * cv[k], bf_hi(xq[k].x) * cv[k]);
      aq[1] = pack_trunc(bf_lo(xq[k].y) * cv[k], bf_hi(xq[k].y) * cv[k]);
      aq[2] = pack_trunc(bf_lo(xq[k].z) * cv[k], bf_hi(xq[k].z) * cv[k]);
      aq[3] = pack_trunc(bf_lo(xq[k].w) * cv[k], bf_hi(xq[k].w) * cv[k]);
      u4s8 bw; bw.u = wf[k];
      acc = __builtin_amdgcn_mfma_f32_16x16x32_bf16(af, bw.s, acc, 0, 0, 0);
    }
  }
  // s_part[btile][j][b=quad*4+rr][ch36][d=col] via device-scope (IC-coherent)
  // stores — readable by tail workers on other XCDs without L2 flushes.
  {
    float* sp = s_part + ((((size_t)blockIdx.x * 10 + wave) * 16 + quad * 4) * 36
                          + blockIdx.y) * 16 + col;
    #pragma unroll
    for (int rr = 0; rr < 4; ++rr)
      __hip_atomic_store(&sp[rr * 576], acc[rr],
                         __ATOMIC_RELAXED, __HIP_MEMORY_SCOPE_AGENT);
  }

  // ---- fused squash tail: last NWORK arrivals do the reduction ----
  __syncthreads();                      // drains vmcnt -> our stores are at IC
  if (tid == 0)
    tick_s = (int)__hip_atomic_fetch_add(&cnt[round], 1u,
                                         __ATOMIC_ACQ_REL, __HIP_MEMORY_SCOPE_AGENT);
  __syncthreads();
  const int ticket = tick_s;
  if (ticket < NBLK - NWORK) return;    // not a worker
  const int wid = ticket - (NBLK - NWORK);
  if (tid == 0) {
    while (__hip_atomic_load(&cnt[round], __ATOMIC_ACQUIRE,
                             __HIP_MEMORY_SCOPE_AGENT) < NBLK)
      __builtin_amdgcn_s_sleep(8);
  }
  __syncthreads();

  const int bjl = tid >> 4;             // 0..39
  const int d   = tid & 15;
  const int bj  = wid * 40 + bjl;       // 64 workers x 40 = all 2560 (b,j)
  const int b = bj / 10, j = bj - b * 10;
  const int btile = b >> 4, brem = b & 15;
  float* basep = s_part + ((((size_t)btile * 10 + j) * 16 + brem) * 36) * 16 + d;
  float s = 0.f;
  #pragma unroll
  for (int ch = 0; ch < 36; ++ch)
    s += __hip_atomic_load(&basep[ch * 16], __ATOMIC_RELAXED,
                           __HIP_MEMORY_SCOPE_AGENT);
  float sq = s * s;
  sq += __shfl_xor(sq, 1, 16);
  sq += __shfl_xor(sq, 2, 16);
  sq += __shfl_xor(sq, 4, 16);
  sq += __shfl_xor(sq, 8, 16);
  const float coef = (sq / (1.f + sq)) * rsqrtf(sq + 1e-7f);
  const float v = coef * s;
  if (round < 2) {
    const float vt = vsum[bj * 16 + d] + v;       // ACCUMULATED v (R7 lesson)
    const float vtn = __shfl_down(vt, 1, 64);     // partner d+1, same 16-group
    vsum[bj * 16 + d] = vt;
    if (!(d & 1)) vsbf_u[bj * 8 + (d >> 1)] = pack_rne(vt, vtn);
  } else {
    out[bj * 16 + d] = v;
  }
}

extern "C" void kernel_launch(void* const* d_in, const int* in_sizes, int n_in,
                              void* d_out, int out_size, void* d_ws, size_t ws_size,
                              hipStream_t stream)
{
  const float* x_p = (const float*)d_in[0];   // [256][1152][8] fp32
  const float* W_p = (const float*)d_in[1];   // [10][1152][16][8] fp32

  // ws: wsf 2.95M | wcc2 2.95M | xbf_ib 4.72M | xbf_bi 4.72M | s_part 5.9M
  //     | vsum 164K | vsbf 82K | cnt 16B   (~21.5 MB)
  uint4* wsf    = (uint4*)d_ws;
  uint4* wcc2   = wsf + 184320;
  uint4* xbf_ib = wcc2 + 184320;
  uint4* xbf_bi = xbf_ib + 294912;
  float* s_prt  = (float*)(xbf_bi + 294912);          // 1474560 f
  float* vsum   = s_prt + 1474560;                    // 40960 f
  unsigned int* vsbf_u = (unsigned int*)(vsum + 40960);   // 20480 u
  unsigned int* cnt    = vsbf_u + 20480;              // 4 u
  float* out_p  = (float*)d_out;

  caps_prep<<<dim3(1008), dim3(256), 0, stream>>>(W_p, x_p, wsf, wcc2,
                                                  xbf_ib, xbf_bi, vsum, cnt);
  for (int r = 0; r < 3; ++r) {
    caps_round<<<dim3(16, 36), dim3(640), 0, stream>>>(
        xbf_ib, xbf_bi, wsf, wcc2, (const uint4*)vsbf_u, s_prt,
        vsum, vsbf_u, out_p, cnt, r);
  }
}

// Round 13
// 126.466 us; speedup vs baseline: 6.0971x; 1.3237x over previous
//
#include <hip/hip_runtime.h>

#define B_N 256
#define IC_N 1152
#define J_N 10
#define D_N 16

typedef __attribute__((ext_vector_type(8))) short short8;
typedef __attribute__((ext_vector_type(4))) float floatx4;

union u4s8 { uint4 u; short8 s; };

__device__ __forceinline__ float bf_lo(unsigned int u){
  union { unsigned int i; float f; } c; c.i = u << 16; return c.f;
}
__device__ __forceinline__ float bf_hi(unsigned int u){
  union { unsigned int i; float f; } c; c.i = u & 0xffff0000u; return c.f;
}
__device__ __forceinline__ unsigned int rne16(float f){
  union { float ff; unsigned int i; } c; c.ff = f;
  return (c.i + 0x7FFFu + ((c.i >> 16) & 1u)) >> 16;
}
__device__ __forceinline__ unsigned int pack_rne(float lo, float hi){
  return rne16(lo) | (rne16(hi) << 16);
}
__device__ __forceinline__ unsigned int pack_trunc(float lo, float hi){
  union { float f; unsigned int u; } a, b; a.f = lo; b.f = hi;
  return __builtin_amdgcn_perm(b.u, a.u, 0x07060302u);
}

// prep (R9-proven, unchanged): W read once -> wsf/wcc2 frags; x -> both
// xbf layouts; zero vsum.
__global__ __launch_bounds__(256) void caps_prep(
    const float* __restrict__ W, const float* __restrict__ x,
    uint4* __restrict__ wsf, uint4* __restrict__ wcc2,
    uint4* __restrict__ xbf_ib, uint4* __restrict__ xbf_bi,
    float* __restrict__ vsum)
{
  const int tid = threadIdx.x;
  if (blockIdx.x < 720) {
    __shared__ unsigned int lw[1024];
    const int j = blockIdx.x / 72, itile = blockIdx.x % 72;
    const float4* Wt = (const float4*)(W + ((size_t)(j * IC_N + itile * 16) << 7));
    #pragma unroll
    for (int h = 0; h < 2; ++h) {
      const float4 f = Wt[h * 256 + tid];
      lw[(h * 256 + tid) * 2]     = pack_rne(f.x, f.y);
      lw[(h * 256 + tid) * 2 + 1] = pack_rne(f.z, f.w);
    }
    __syncthreads();
    {  // wsf emit (layout verified R5..R9)
      const int ktl = tid >> 6, ln = tid & 63;
      const int base = (ktl * 4 + (ln >> 4)) * 64 + (ln & 15) * 4;
      uint4 q;
      q.x = lw[base]; q.y = lw[base + 1]; q.z = lw[base + 2]; q.w = lw[base + 3];
      wsf[((size_t)j * 288 + itile * 4 + ktl) * 64 + ln] = q;
    }
    {  // wcc2 emit (layout verified R6..R9)
      const int e = tid >> 5, lane2 = tid & 31;
      const int il = lane2 & 15, dbase = (lane2 >> 4) * 8;
      unsigned short h[8];
      #pragma unroll
      for (int k = 0; k < 8; ++k) {
        const unsigned int u = lw[il * 64 + (dbase + k) * 4 + (e >> 1)];
        h[k] = (e & 1) ? (unsigned short)(u >> 16) : (unsigned short)(u & 0xffffu);
      }
      uint4 q;
      q.x = h[0] | ((unsigned int)h[1] << 16);
      q.y = h[2] | ((unsigned int)h[3] << 16);
      q.z = h[4] | ((unsigned int)h[5] << 16);
      q.w = h[6] | ((unsigned int)h[7] << 16);
      wcc2[(((size_t)j * 8 + e) * 72 + itile) * 32 + lane2] = q;
    }
  } else {
    __shared__ unsigned int tx[4][64 * 17];
    const int xb = blockIdx.x - 720;
    const int t0 = xb * 256 + tid;
    if (t0 < B_N * J_N * D_N) vsum[t0] = 0.f;
    const int b0 = (xb / 18) * 16;
    const int i0 = (xb % 18) * 64;
    #pragma unroll
    for (int r = 0; r < 4; ++r) {
      const int bl = r * 4 + (tid >> 6);
      const int il = tid & 63;
      const float4* sp = (const float4*)(x + ((size_t)((b0 + bl) * IC_N + i0 + il) << 3));
      const float4 a = sp[0], c = sp[1];
      uint4 q;
      q.x = pack_rne(a.x, a.y); q.y = pack_rne(a.z, a.w);
      q.z = pack_rne(c.x, c.y); q.w = pack_rne(c.z, c.w);
      xbf_bi[(size_t)(b0 + bl) * IC_N + i0 + il] = q;
      tx[0][il * 17 + bl] = q.x; tx[1][il * 17 + bl] = q.y;
      tx[2][il * 17 + bl] = q.z; tx[3][il * 17 + bl] = q.w;
    }
    __syncthreads();
    #pragma unroll
    for (int it = 0; it < 4; ++it) {
      const int p  = it * 256 + tid;
      const int il = p >> 4, bl = p & 15;
      uint4 q;
      q.x = tx[0][il * 17 + bl]; q.y = tx[1][il * 17 + bl];
      q.z = tx[2][il * 17 + bl]; q.w = tx[3][il * 17 + bl];
      xbf_ib[(size_t)(i0 + il) * 256 + b0 + bl] = q;
    }
  }
}

// Pass (R9 math, two perf changes):
//  1. flat 1152-grid with XCD swizzle: XCD g = bid&7 owns chunks [9g,9g+9)
//     x all 16 btiles -> per-XCD working set ~2MB, L2-resident.
//  2. phase-B xq/wf loads hoisted above phase A (independent; the barrier
//     fence pins them) -> one latency clump instead of three.
__global__ __launch_bounds__(640, 5) void caps_pass(
    const uint4* __restrict__ xbf_ib, const uint4* __restrict__ xbf_bi,
    const uint4* __restrict__ wsf, const uint4* __restrict__ wcc2,
    const uint4* __restrict__ vsbf, float* __restrict__ s_part, const int round)
{
  __shared__ float ccl[10 * 16 * 17];   // [j][i_local][b pad17]
  const int tid  = threadIdx.x;
  const int wave = tid >> 6;            // = j
  const int lane = tid & 63;
  const int quad = lane >> 4;
  const int col  = lane & 15;
  const int bid  = blockIdx.x;          // 0..1151
  const int g    = bid & 7;             // XCD (perf heuristic only)
  const int rr0  = bid >> 3;            // 0..143
  const int btile = rr0 & 15;
  const int chunk = g * 9 + (rr0 >> 4); // bijective over [0,72)
  const int b0 = btile << 4, i0 = chunk << 4;

  // ---- hoisted phase-B loads (independent of phase A) ----
  uint4 xq[4], wf[4];
  #pragma unroll
  for (int kt = 0; kt < 4; ++kt) {
    const int il = kt * 4 + quad;
    xq[kt] = xbf_ib[(size_t)(i0 + il) * 256 + b0 + col];
    wf[kt] = wsf[((size_t)wave * 288 + (chunk << 2) + kt) * 64 + lane];
  }

  if (round > 0) {
    short8 av = {0,0,0,0,0,0,0,0};      // vsum[b=col][d=quad*8+..]; q2,3 K-pad
    if (quad < 2)
      av = *(const short8*)&vsbf[((size_t)(b0 + col) * J_N + wave) * 2 + quad];
    uint4 bvq[8];
    #pragma unroll
    for (int e = 0; e < 8; ++e) {
      uint4 q = {0u, 0u, 0u, 0u};
      if (lane < 32)
        q = wcc2[(((size_t)wave * 8 + e) * 72 + chunk) * 32 + lane];
      bvq[e] = q;
    }
    uint4 xr[4];
    #pragma unroll
    for (int r = 0; r < 4; ++r)
      xr[r] = xbf_bi[(size_t)(b0 + quad * 4 + r) * IC_N + i0 + col];
    floatx4 cc4 = {0.f, 0.f, 0.f, 0.f};
    #pragma unroll
    for (int e = 0; e < 8; ++e) {
      u4s8 bv; bv.u = bvq[e];
      floatx4 tf = {0.f, 0.f, 0.f, 0.f};
      tf = __builtin_amdgcn_mfma_f32_16x16x32_bf16(av, bv.s, tf, 0, 0, 0);
      #pragma unroll
      for (int r = 0; r < 4; ++r) {
        const unsigned int u = ((const unsigned int*)&xr[r])[e >> 1];
        const float xe = (e & 1) ? bf_hi(u) : bf_lo(u);
        cc4[r] += tf[r] * xe;
      }
    }
    #pragma unroll
    for (int r = 0; r < 4; ++r)
      ccl[(wave * 16 + col) * 17 + quad * 4 + r] = cc4[r];
    __syncthreads();
    if (tid < 256) {                    // softmax over j per (i,b), in place
      const int i = tid >> 4, b = tid & 15;
      float cc[10];
      #pragma unroll
      for (int j = 0; j < 10; ++j) cc[j] = ccl[(j * 16 + i) * 17 + b];
      float m = cc[0];
      #pragma unroll
      for (int j = 1; j < 10; ++j) m = fmaxf(m, cc[j]);
      float den = 0.f;
      #pragma unroll
      for (int j = 0; j < 10; ++j) { cc[j] = __expf(cc[j] - m); den += cc[j]; }
      const float rd = __builtin_amdgcn_rcpf(den);
      #pragma unroll
      for (int j = 0; j < 10; ++j) ccl[(j * 16 + i) * 17 + b] = cc[j] * rd;
    }
    __syncthreads();
  }

  // Phase B: s[b,d] += (c*x) @ Ws, K=128 — loads already in registers
  floatx4 acc = {0.f, 0.f, 0.f, 0.f};
  #pragma unroll
  for (int kt = 0; kt < 4; ++kt) {
    const int il = kt * 4 + quad;
    const float c = (round > 0) ? ccl[(wave * 16 + il) * 17 + col] : 0.1f;
    short8 af;
    unsigned int* aq = (unsigned int*)&af;
    aq[0] = pack_trunc(bf_lo(xq[kt].x) * c, bf_hi(xq[kt].x) * c);
    aq[1] = pack_trunc(bf_lo(xq[kt].y) * c, bf_hi(xq[kt].y) * c);
    aq[2] = pack_trunc(bf_lo(xq[kt].z) * c, bf_hi(xq[kt].z) * c);
    aq[3] = pack_trunc(bf_lo(xq[kt].w) * c, bf_hi(xq[kt].w) * c);
    u4s8 bw; bw.u = wf[kt];
    acc = __builtin_amdgcn_mfma_f32_16x16x32_bf16(af, bw.s, acc, 0, 0, 0);
  }
  // s_part[btile][j][b=quad*4+r][ch72][d=col]  (R9 layout, squash-compatible)
  float* sp = s_part + ((((size_t)btile * 10 + wave) * 16 + quad * 4) * 72
                        + chunk) * 16 + col;
  #pragma unroll
  for (int r = 0; r < 4; ++r) sp[(size_t)r * 72 * 16] = acc[r];
}

// squash (R9-proven, unchanged): one wave per (b,j); 18 coalesced loads;
// vsbf holds ACCUMULATED v-sum (R7 lesson).
__global__ __launch_bounds__(256) void caps_squash(
    const float* __restrict__ s_part, float* __restrict__ vsum,
    unsigned int* __restrict__ vsbf_u, float* __restrict__ out, const int round)
{
  const int tid  = threadIdx.x;
  const int w    = tid >> 6;
  const int lane = tid & 63;
  const int bj   = blockIdx.x * 4 + w;
  const int b    = bj / 10, j = bj - b * 10;
  const int btile = b >> 4, brem = b & 15;
  const float* base = s_part + (((size_t)btile * 10 + j) * 16 + brem) * 1152;
  float acc = 0.f;
  #pragma unroll
  for (int q = 0; q < 18; ++q) acc += base[q * 64 + lane];
  acc += __shfl_xor(acc, 16, 64);
  acc += __shfl_xor(acc, 32, 64);
  const float s = acc;
  float sq = s * s;
  sq += __shfl_xor(sq, 1, 16);
  sq += __shfl_xor(sq, 2, 16);
  sq += __shfl_xor(sq, 4, 16);
  sq += __shfl_xor(sq, 8, 16);
  const float coef = (sq / (1.f + sq)) * rsqrtf(sq + 1e-7f);
  const float v = coef * s;
  if (round < 2) {
    const float vprev = (lane < 16) ? vsum[bj * 16 + lane] : 0.f;
    const float vt = vprev + v;
    const float vtn = __shfl_down(vt, 1, 64);
    if (lane < 16) {
      vsum[bj * 16 + lane] = vt;
      if (!(lane & 1))
        vsbf_u[bj * 8 + (lane >> 1)] = pack_rne(vt, vtn);
    }
  } else if (lane < 16) {
    out[bj * 16 + lane] = v;
  }
}

extern "C" void kernel_launch(void* const* d_in, const int* in_sizes, int n_in,
                              void* d_out, int out_size, void* d_ws, size_t ws_size,
                              hipStream_t stream)
{
  const float* x_p = (const float*)d_in[0];   // [256][1152][8] fp32
  const float* W_p = (const float*)d_in[1];   // [10][1152][16][8] fp32

  // ws: wsf 2.95M | wcc2 2.95M | xbf_ib 4.72M | xbf_bi 4.72M | s_part 11.8M
  //     | vsum 164K | vsbf 82K
  uint4* wsf    = (uint4*)d_ws;
  uint4* wcc2   = wsf + 184320;
  uint4* xbf_ib = wcc2 + 184320;
  uint4* xbf_bi = xbf_ib + 294912;
  float* s_prt  = (float*)(xbf_bi + 294912);          // 2949120 f
  float* vsum   = s_prt + 2949120;                    // 40960 f
  unsigned int* vsbf_u = (unsigned int*)(vsum + 40960);
  float* out_p  = (float*)d_out;

  caps_prep<<<dim3(1008), dim3(256), 0, stream>>>(W_p, x_p, wsf, wcc2,
                                                  xbf_ib, xbf_bi, vsum);
  for (int r = 0; r < 3; ++r) {
    caps_pass<<<dim3(1152), dim3(640), 0, stream>>>(
        xbf_ib, xbf_bi, wsf, wcc2, (const uint4*)vsbf_u, s_prt, r);
    caps_squash<<<dim3(640), dim3(256), 0, stream>>>(
        s_prt, vsum, vsbf_u, out_p, r);
  }
}

// Round 14
// 115.712 us; speedup vs baseline: 6.6638x; 1.0929x over previous
//
#include <hip/hip_runtime.h>

#define B_N 256
#define IC_N 1152
#define J_N 10
#define D_N 16

typedef __attribute__((ext_vector_type(8))) short short8;
typedef __attribute__((ext_vector_type(4))) float floatx4;

union u4s8 { uint4 u; short8 s; };

__device__ __forceinline__ float bf_lo(unsigned int u){
  union { unsigned int i; float f; } c; c.i = u << 16; return c.f;
}
__device__ __forceinline__ float bf_hi(unsigned int u){
  union { unsigned int i; float f; } c; c.i = u & 0xffff0000u; return c.f;
}
__device__ __forceinline__ unsigned int rne16(float f){
  union { float ff; unsigned int i; } c; c.ff = f;
  return (c.i + 0x7FFFu + ((c.i >> 16) & 1u)) >> 16;
}
__device__ __forceinline__ unsigned int pack_rne(float lo, float hi){
  return rne16(lo) | (rne16(hi) << 16);
}
__device__ __forceinline__ unsigned int pack_trunc(float lo, float hi){
  union { float f; unsigned int u; } a, b; a.f = lo; b.f = hi;
  return __builtin_amdgcn_perm(b.u, a.u, 0x07060302u);
}

// prep: W-only now (x staging removed — passes stage x themselves in LDS).
// 720 blocks: (j, itile16) -> wsf + wcc2 frags; first 160 blocks also zero vsum.
__global__ __launch_bounds__(256) void caps_prep(
    const float* __restrict__ W, uint4* __restrict__ wsf,
    uint4* __restrict__ wcc2, float* __restrict__ vsum)
{
  const int tid = threadIdx.x;
  const int t0 = blockIdx.x * 256 + tid;
  if (t0 < B_N * J_N * D_N) vsum[t0] = 0.f;
  __shared__ unsigned int lw[1024];
  const int j = blockIdx.x / 72, itile = blockIdx.x % 72;
  const float4* Wt = (const float4*)(W + ((size_t)(j * IC_N + itile * 16) << 7));
  #pragma unroll
  for (int h = 0; h < 2; ++h) {
    const float4 f = Wt[h * 256 + tid];
    lw[(h * 256 + tid) * 2]     = pack_rne(f.x, f.y);
    lw[(h * 256 + tid) * 2 + 1] = pack_rne(f.z, f.w);
  }
  __syncthreads();
  {  // wsf emit (layout verified R5..R13)
    const int ktl = tid >> 6, ln = tid & 63;
    const int base = (ktl * 4 + (ln >> 4)) * 64 + (ln & 15) * 4;
    uint4 q;
    q.x = lw[base]; q.y = lw[base + 1]; q.z = lw[base + 2]; q.w = lw[base + 3];
    wsf[((size_t)j * 288 + itile * 4 + ktl) * 64 + ln] = q;
  }
  {  // wcc2 emit (layout verified R6..R13)
    const int e = tid >> 5, lane2 = tid & 31;
    const int il = lane2 & 15, dbase = (lane2 >> 4) * 8;
    unsigned short h[8];
    #pragma unroll
    for (int k = 0; k < 8; ++k) {
      const unsigned int u = lw[il * 64 + (dbase + k) * 4 + (e >> 1)];
      h[k] = (e & 1) ? (unsigned short)(u >> 16) : (unsigned short)(u & 0xffffu);
    }
    uint4 q;
    q.x = h[0] | ((unsigned int)h[1] << 16);
    q.y = h[2] | ((unsigned int)h[3] << 16);
    q.z = h[4] | ((unsigned int)h[5] << 16);
    q.w = h[6] | ((unsigned int)h[7] << 16);
    wcc2[(((size_t)j * 8 + e) * 72 + itile) * 32 + lane2] = q;
  }
}

// Pass (R9 backbone: grid (16,72), 640 thr, 16-i chunks). x comes straight
// from the fp32 input: one coalesced 8 KB tile -> LDS xt[i][b pad17] (uint4
// packed bf16), serving BOTH phase-A (lanes=i) and phase-B (lanes=b) reads
// at LDS latency. No xbf buffers, no cross-barrier register hoists.
__global__ __launch_bounds__(640, 5) void caps_pass(
    const float* __restrict__ x,
    const uint4* __restrict__ wsf, const uint4* __restrict__ wcc2,
    const uint4* __restrict__ vsbf, float* __restrict__ s_part, const int round)
{
  __shared__ float ccl[10 * 16 * 17];     // 10.6 KB
  __shared__ unsigned int xt[16 * 17 * 4];// [i][b pad17] uint4, 4.3 KB

  const int tid  = threadIdx.x;
  const int wave = tid >> 6;              // = j
  const int lane = tid & 63;
  const int quad = lane >> 4;
  const int col  = lane & 15;
  const int b0   = blockIdx.x << 4;
  const int i0   = blockIdx.y << 4;       // 16 i per chunk

  // ---- stage x tile: 512 threads, 512-B coalesced runs per b-row ----
  if (tid < 512) {
    const int b = tid >> 5, j4 = tid & 31;
    const int i = j4 >> 1, half = j4 & 1;
    const float4 v = ((const float4*)(x + ((size_t)((b0 + b) * IC_N + i0 + i) << 3)))[half];
    const int idx = ((i * 17 + b) << 2) + (half << 1);
    xt[idx]     = pack_rne(v.x, v.y);
    xt[idx + 1] = pack_rne(v.z, v.w);
  }
  __syncthreads();
  const uint4* xtq = (const uint4*)xt;

  if (round > 0) {
    short8 av = {0,0,0,0,0,0,0,0};        // vsum[b=col][d=quad*8+..]; q2,3 pad
    if (quad < 2)
      av = *(const short8*)&vsbf[((size_t)(b0 + col) * J_N + wave) * 2 + quad];
    uint4 bvq[8];
    #pragma unroll
    for (int e = 0; e < 8; ++e) {
      uint4 q = {0u, 0u, 0u, 0u};
      if (lane < 32)
        q = wcc2[(((size_t)wave * 8 + e) * 72 + blockIdx.y) * 32 + lane];
      bvq[e] = q;
    }
    uint4 xr[4];                          // x[b=quad*4+r][i=col] from LDS
    #pragma unroll
    for (int r = 0; r < 4; ++r)
      xr[r] = xtq[col * 17 + quad * 4 + r];
    floatx4 cc4 = {0.f, 0.f, 0.f, 0.f};
    #pragma unroll
    for (int e = 0; e < 8; ++e) {
      u4s8 bv; bv.u = bvq[e];
      floatx4 tf = {0.f, 0.f, 0.f, 0.f};
      tf = __builtin_amdgcn_mfma_f32_16x16x32_bf16(av, bv.s, tf, 0, 0, 0);
      #pragma unroll
      for (int r = 0; r < 4; ++r) {
        const unsigned int u = ((const unsigned int*)&xr[r])[e >> 1];
        const float xe = (e & 1) ? bf_hi(u) : bf_lo(u);
        cc4[r] += tf[r] * xe;
      }
    }
    #pragma unroll
    for (int r = 0; r < 4; ++r)
      ccl[(wave * 16 + col) * 17 + quad * 4 + r] = cc4[r];
    __syncthreads();
    if (tid < 256) {                      // softmax over j per (i,b), in place
      const int i = tid >> 4, b = tid & 15;
      float cc[10];
      #pragma unroll
      for (int j = 0; j < 10; ++j) cc[j] = ccl[(j * 16 + i) * 17 + b];
      float m = cc[0];
      #pragma unroll
      for (int j = 1; j < 10; ++j) m = fmaxf(m, cc[j]);
      float den = 0.f;
      #pragma unroll
      for (int j = 0; j < 10; ++j) { cc[j] = __expf(cc[j] - m); den += cc[j]; }
      const float rd = __builtin_amdgcn_rcpf(den);
      #pragma unroll
      for (int j = 0; j < 10; ++j) ccl[(j * 16 + i) * 17 + b] = cc[j] * rd;
    }
    __syncthreads();
  }

  // Phase B: s[b,d] += (c*x) @ Ws, K=128; x from LDS, W from global (L2-warm)
  floatx4 acc = {0.f, 0.f, 0.f, 0.f};
  #pragma unroll
  for (int kt = 0; kt < 4; ++kt) {
    const int il = kt * 4 + quad;
    const uint4 xq = xtq[il * 17 + col];  // x[i=il][b=col]
    const uint4 wf = wsf[((size_t)wave * 288 + (blockIdx.y << 2) + kt) * 64 + lane];
    const float c = (round > 0) ? ccl[(wave * 16 + il) * 17 + col] : 0.1f;
    short8 af;
    unsigned int* aq = (unsigned int*)&af;
    aq[0] = pack_trunc(bf_lo(xq.x) * c, bf_hi(xq.x) * c);
    aq[1] = pack_trunc(bf_lo(xq.y) * c, bf_hi(xq.y) * c);
    aq[2] = pack_trunc(bf_lo(xq.z) * c, bf_hi(xq.z) * c);
    aq[3] = pack_trunc(bf_lo(xq.w) * c, bf_hi(xq.w) * c);
    u4s8 bw; bw.u = wf;
    acc = __builtin_amdgcn_mfma_f32_16x16x32_bf16(af, bw.s, acc, 0, 0, 0);
  }
  // s_part[btile][j][b=quad*4+r][ch72][d=col]
  float* sp = s_part + ((((size_t)blockIdx.x * 10 + wave) * 16 + quad * 4) * 72
                        + blockIdx.y) * 16 + col;
  #pragma unroll
  for (int r = 0; r < 4; ++r) sp[(size_t)r * 72 * 16] = acc[r];
}

// squash (R9-proven, unchanged): one wave per (b,j); 18 coalesced loads;
// vsbf holds ACCUMULATED v-sum (R7 lesson).
__global__ __launch_bounds__(256) void caps_squash(
    const float* __restrict__ s_part, float* __restrict__ vsum,
    unsigned int* __restrict__ vsbf_u, float* __restrict__ out, const int round)
{
  const int tid  = threadIdx.x;
  const int w    = tid >> 6;
  const int lane = tid & 63;
  const int bj   = blockIdx.x * 4 + w;
  const int b    = bj / 10, j = bj - b * 10;
  const int btile = b >> 4, brem = b & 15;
  const float* base = s_part + (((size_t)btile * 10 + j) * 16 + brem) * 1152;
  float acc = 0.f;
  #pragma unroll
  for (int q = 0; q < 18; ++q) acc += base[q * 64 + lane];
  acc += __shfl_xor(acc, 16, 64);
  acc += __shfl_xor(acc, 32, 64);
  const float s = acc;
  float sq = s * s;
  sq += __shfl_xor(sq, 1, 16);
  sq += __shfl_xor(sq, 2, 16);
  sq += __shfl_xor(sq, 4, 16);
  sq += __shfl_xor(sq, 8, 16);
  const float coef = (sq / (1.f + sq)) * rsqrtf(sq + 1e-7f);
  const float v = coef * s;
  if (round < 2) {
    const float vprev = (lane < 16) ? vsum[bj * 16 + lane] : 0.f;
    const float vt = vprev + v;
    const float vtn = __shfl_down(vt, 1, 64);
    if (lane < 16) {
      vsum[bj * 16 + lane] = vt;
      if (!(lane & 1))
        vsbf_u[bj * 8 + (lane >> 1)] = pack_rne(vt, vtn);
    }
  } else if (lane < 16) {
    out[bj * 16 + lane] = v;
  }
}

extern "C" void kernel_launch(void* const* d_in, const int* in_sizes, int n_in,
                              void* d_out, int out_size, void* d_ws, size_t ws_size,
                              hipStream_t stream)
{
  const float* x_p = (const float*)d_in[0];   // [256][1152][8] fp32
  const float* W_p = (const float*)d_in[1];   // [10][1152][16][8] fp32

  // ws: wsf 2.95M | wcc2 2.95M | s_part 11.8M | vsum 164K | vsbf 82K (~18 MB)
  uint4* wsf   = (uint4*)d_ws;
  uint4* wcc2  = wsf + 184320;
  float* s_prt = (float*)(wcc2 + 184320);             // 2949120 f
  float* vsum  = s_prt + 2949120;                     // 40960 f
  unsigned int* vsbf_u = (unsigned int*)(vsum + 40960);
  float* out_p = (float*)d_out;

  caps_prep<<<dim3(720), dim3(256), 0, stream>>>(W_p, wsf, wcc2, vsum);
  for (int r = 0; r < 3; ++r) {
    caps_pass<<<dim3(16, 72), dim3(640), 0, stream>>>(
        x_p, wsf, wcc2, (const uint4*)vsbf_u, s_prt, r);
    caps_squash<<<dim3(640), dim3(256), 0, stream>>>(
        s_prt, vsum, vsbf_u, out_p, r);
  }
}